// Round 3
// baseline (2619.507 us; speedup 1.0000x reference)
//
#include <hip/hip_runtime.h>

// LSTMencoder: 2-layer biLSTM, B=256, T=2048, H=32 (4H=128 gates), in=32/64.
//
// Path A: time-chunked xg precompute (gemm) + slim serial recurrence.
//   R2 finding: rec VGPR_Count=56 < 64 floats of Whh alone -> compiler
//   rematerialized weight loads every step (~64 loads/step on the serial
//   chain). Fix: asm-pin Whh in VGPRs; hoist lane-constant nonlin selects;
//   incremental pointers; gemm switched from LDS-staged x (ds_read_b128
//   bound) to wave-uniform s_load x, no LDS, acc[16] ILP.
// Path B fallback: harness-verified fused kernel (tiny ws).

#define T_LEN 2048
#define BATCH 256
#define HID   32
#define PF    8

__device__ __forceinline__ float frcp(float x) { return __builtin_amdgcn_rcpf(x); }
__device__ __forceinline__ float rdlane(float v, int k) {
    return __int_as_float(__builtin_amdgcn_readlane(__float_as_int(v), k));
}

template<int N>
__device__ __forceinline__ void load_row(float* dst, const float* __restrict__ src) {
#pragma unroll
    for (int i = 0; i < N / 4; ++i) {
        float4 v = reinterpret_cast<const float4*>(src)[i];
        dst[4*i+0] = v.x; dst[4*i+1] = v.y; dst[4*i+2] = v.z; dst[4*i+3] = v.w;
    }
}

// ===================== Path A: chunked xg precompute GEMM =====================
// thread (d,g) computes xg for 16 timesteps of one b. x rows are wave-uniform
// (d readfirstlane'd) -> s_load; W row chunk in VGPRs; acc[16] ILP.
template<int LAYER>
__global__ __launch_bounds__(256) void xg_gemm_chunk(
        const float* __restrict__ OS, const float* __restrict__ IS,
        const float* __restrict__ h1,
        const float* __restrict__ Wih, const float* __restrict__ bih,
        const float* __restrict__ bhh, float* __restrict__ xg,
        int t_base, int C)
{
    constexpr int F  = (LAYER == 0) ? 32 : 64;
    constexpr int TT = 16;
    const int tid = threadIdx.x;
    const int d   = __builtin_amdgcn_readfirstlane(tid >> 7);   // wave-uniform
    const int g   = tid & 127;
    const int lt0 = blockIdx.x * TT;
    const int b   = blockIdx.y;

    const float bias = bih[d * 128 + g] + bhh[d * 128 + g];
    float acc[TT];
#pragma unroll
    for (int tt = 0; tt < TT; ++tt) acc[tt] = bias;

    const float* wrow = Wih + ((size_t)d * 128 + g) * F;

#pragma unroll
    for (int fc = 0; fc < F; fc += 16) {
        float w16[16];
        load_row<16>(w16, wrow + fc);
#pragma unroll
        for (int tt = 0; tt < TT; ++tt) {
            const int tl = t_base + lt0 + tt;
            const int te = d ? (T_LEN - 1 - tl) : tl;
            const float* xr;
            if constexpr (LAYER == 0) {
                xr = (fc == 0) ? (OS + ((size_t)b * T_LEN + te) * 16)
                               : (IS + ((size_t)b * T_LEN + (T_LEN - 1 - te)) * 16);
            } else {
                xr = h1 + ((size_t)te * BATCH + b) * 64 + fc;
            }
            // uniform address -> scalar loads; SGPR operand in the FMAs
#pragma unroll
            for (int j = 0; j < 4; ++j) {
                float4 xv = reinterpret_cast<const float4*>(xr)[j];
                acc[tt] = fmaf(xv.x, w16[4*j+0], acc[tt]);
                acc[tt] = fmaf(xv.y, w16[4*j+1], acc[tt]);
                acc[tt] = fmaf(xv.z, w16[4*j+2], acc[tt]);
                acc[tt] = fmaf(xv.w, w16[4*j+3], acc[tt]);
            }
        }
    }
#pragma unroll
    for (int tt = 0; tt < TT; ++tt)
        xg[(((size_t)d * C + (lt0 + tt)) * BATCH + b) * 128 + g] = acc[tt];
}

// ===================== Path A: chunked serial recurrence =====================
template<int LAYER>
__global__ __launch_bounds__(64, 1) void lstm_rec_chunk(
        const float* __restrict__ xg, const float* __restrict__ Whh,
        float* __restrict__ outp, float* __restrict__ state,
        int t_base, int C)
{
    const int l   = threadIdx.x;     // 0..63
    const int b   = blockIdx.x;      // 0..255
    const int d   = blockIdx.y;      // 0 fwd, 1 bwd
    const bool lo = (l < HID);
    const int chain = d * BATCH + b;
    const int xl  = (l + 32) & 63;   // swap partner

    // lane-constant nonlinearity params (hoisted: no per-step selects)
    const float mB = lo ? -2.f : -1.f;   // tanh arg scale (g) vs sigmoid (o)
    const float kM = lo ?  2.f :  1.f;
    const float kA = lo ? -1.f :  0.f;

    float wa[HID], wb[HID];
    load_row<HID>(wa, Whh + ((size_t)d * 128 + l) * HID);
    load_row<HID>(wb, Whh + ((size_t)d * 128 + 64 + l) * HID);

    // restore state (zeros at t_base==0)
    float c = 0.f, hj = 0.f;
    if (t_base > 0 && lo) {
        c  = state[(size_t)chain * 64 + l];
        hj = state[(size_t)chain * 64 + 32 + l];
    }
    float h[HID];                    // wave-uniform via readlane (SGPRs)
#pragma unroll
    for (int k = 0; k < HID; ++k) h[k] = rdlane(hj, k);

    const size_t STRIDE = (size_t)BATCH * 128;
    const float* xp = xg + (size_t)d * C * STRIDE + (size_t)b * 128;
    const float* pf = xp + (size_t)PF * STRIDE;   // prefetch cursor

    float ra[PF], rb[PF];
#pragma unroll
    for (int u = 0; u < PF; ++u) {
        ra[u] = xp[(size_t)u * STRIDE + l];
        rb[u] = xp[(size_t)u * STRIDE + 64 + l];
    }

    // incremental output pointer
    const int te0 = d ? (T_LEN - 1 - t_base) : t_base;
    float* op;
    ptrdiff_t ostep;
    if constexpr (LAYER == 0) {
        op = outp + ((size_t)te0 * BATCH + b) * 64 + d * HID + l;
        ostep = d ? -(ptrdiff_t)(BATCH * 64) : (ptrdiff_t)(BATCH * 64);
    } else {
        op = outp + ((size_t)b * T_LEN + te0) * 64 + d * HID + l;
        ostep = d ? (ptrdiff_t)-64 : (ptrdiff_t)64;
    }

#pragma unroll 1
    for (int tb = 0; tb < C; tb += PF) {
        // pin W in VGPRs: asm redefines values -> compiler cannot remat loads
#pragma unroll
        for (int k = 0; k < HID; k += 4)
            asm volatile("" : "+v"(wa[k]), "+v"(wa[k+1]), "+v"(wa[k+2]), "+v"(wa[k+3]));
#pragma unroll
        for (int k = 0; k < HID; k += 4)
            asm volatile("" : "+v"(wb[k]), "+v"(wb[k+1]), "+v"(wb[k+2]), "+v"(wb[k+3]));

#pragma unroll
        for (int u = 0; u < PF; ++u) {
            const float xa = ra[u], xb = rb[u];
            ra[u] = pf[l];               // prefetch step lt+PF (slack-covered)
            rb[u] = pf[64 + l];
            pf += STRIDE;

            // recurrent dot: 8 independent FMA chains of length 8
            float a0 = xa, a1 = 0.f, a2 = 0.f, a3 = 0.f;
            float b0 = xb, b1 = 0.f, b2 = 0.f, b3 = 0.f;
#pragma unroll
            for (int k = 0; k < 8; ++k) {
                a0 = fmaf(h[k],      wa[k],      a0);
                a1 = fmaf(h[k + 8],  wa[k + 8],  a1);
                a2 = fmaf(h[k + 16], wa[k + 16], a2);
                a3 = fmaf(h[k + 24], wa[k + 24], a3);
                b0 = fmaf(h[k],      wb[k],      b0);
                b1 = fmaf(h[k + 8],  wb[k + 8],  b1);
                b2 = fmaf(h[k + 16], wb[k + 16], b2);
                b3 = fmaf(h[k + 24], wb[k + 24], b3);
            }
            const float accA = (a0 + a1) + (a2 + a3);
            const float accB = (b0 + b1) + (b2 + b3);

            // sA = sigmoid(accA); sB = tanh(accB) [lo] or sigmoid(accB) [hi]
            const float sA = frcp(1.f + __expf(-accA));
            const float rB = frcp(1.f + __expf(mB * accB));
            const float sB = fmaf(kM, rB, kA);
            const float sf = __shfl(sA, xl);    // sig(f) to lanes<32
            const float so = __shfl(sB, xl);    // sig(o) to lanes<32
            c = fmaf(sf, c, sA * sB);
            const float tc = fmaf(2.f, frcp(1.f + __expf(-2.f * c)), -1.f);
            hj = so * tc;
            if (lo) *op = hj;
            op += ostep;
#pragma unroll
            for (int k = 0; k < HID; ++k) h[k] = rdlane(hj, k);
        }
    }

    if (lo) {
        state[(size_t)chain * 64 + l]      = c;
        state[(size_t)chain * 64 + 32 + l] = hj;
    }
}

// ===================== Path B: previous verified fused kernel =====================
template<int LAYER>
__global__ __launch_bounds__(64, 1) void lstm_rec(
        const float* __restrict__ OS, const float* __restrict__ IS,
        const float* __restrict__ Wih, const float* __restrict__ Whh,
        const float* __restrict__ bih, const float* __restrict__ bhh,
        const float* __restrict__ h1in, float* __restrict__ outp)
{
    constexpr int F = (LAYER == 0) ? 32 : 64;
    const int l   = threadIdx.x;
    const int b   = blockIdx.x;
    const int dir = blockIdx.y;
    const int gA  = l;
    const int gB  = 64 + l;

    float wih_a[F], wih_b[F], whh_a[HID], whh_b[HID];
    load_row<F>(wih_a, Wih + ((size_t)dir * 128 + gA) * F);
    load_row<F>(wih_b, Wih + ((size_t)dir * 128 + gB) * F);
    load_row<HID>(whh_a, Whh + ((size_t)dir * 128 + gA) * HID);
    load_row<HID>(whh_b, Whh + ((size_t)dir * 128 + gB) * HID);
    const float biasA = bih[dir * 128 + gA] + bhh[dir * 128 + gA];
    const float biasB = bih[dir * 128 + gB] + bhh[dir * 128 + gB];

    float h[HID];
#pragma unroll
    for (int k = 0; k < HID; ++k) h[k] = 0.f;
    float c = 0.f;
    const bool lo = (l < HID);

    float4 X0[F / 4], X1[F / 4];

    auto load_x = [&](float4* X, int tl) {
        const int te = dir ? (T_LEN - 1 - tl) : tl;
        if constexpr (LAYER == 0) {
            const float4* p0 = reinterpret_cast<const float4*>(OS + ((size_t)b * T_LEN + te) * 16);
            const float4* p1 = reinterpret_cast<const float4*>(IS + ((size_t)b * T_LEN + (T_LEN - 1 - te)) * 16);
#pragma unroll
            for (int i = 0; i < 4; ++i) X[i] = p0[i];
#pragma unroll
            for (int i = 0; i < 4; ++i) X[4 + i] = p1[i];
        } else {
            const float4* p = reinterpret_cast<const float4*>(h1in + ((size_t)te * BATCH + b) * 64);
#pragma unroll
            for (int i = 0; i < F / 4; ++i) X[i] = p[i];
        }
    };

    auto step = [&](int tl, const float4* X) {
        const int te = dir ? (T_LEN - 1 - tl) : tl;
        float accA = biasA, accB = biasB;
#pragma unroll
        for (int i = 0; i < F / 4; ++i) {
            accA = fmaf(X[i].x, wih_a[4*i+0], accA);
            accA = fmaf(X[i].y, wih_a[4*i+1], accA);
            accA = fmaf(X[i].z, wih_a[4*i+2], accA);
            accA = fmaf(X[i].w, wih_a[4*i+3], accA);
            accB = fmaf(X[i].x, wih_b[4*i+0], accB);
            accB = fmaf(X[i].y, wih_b[4*i+1], accB);
            accB = fmaf(X[i].z, wih_b[4*i+2], accB);
            accB = fmaf(X[i].w, wih_b[4*i+3], accB);
        }
#pragma unroll
        for (int k = 0; k < HID; ++k) {
            accA = fmaf(h[k], whh_a[k], accA);
            accB = fmaf(h[k], whh_b[k], accB);
        }
        float sA = frcp(1.f + __expf(-accA));
        float argB = lo ? (-2.f * accB) : (-accB);
        float rB = frcp(1.f + __expf(argB));
        float sB = lo ? fmaf(2.f, rB, -1.f) : rB;
        float sf = __shfl(sA, (l + 32) & 63);
        float so = __shfl(sB, (l + 32) & 63);
        c = fmaf(sf, c, sA * sB);
        float tc = fmaf(2.f, frcp(1.f + __expf(-2.f * c)), -1.f);
        float hj = so * tc;
        if (lo) {
            if constexpr (LAYER == 0)
                outp[((size_t)te * BATCH + b) * 64 + dir * HID + l] = hj;
            else
                outp[((size_t)b * T_LEN + te) * 64 + dir * HID + l] = hj;
        }
#pragma unroll
        for (int k = 0; k < HID; ++k) h[k] = rdlane(hj, k);
    };

    load_x(X0, 0);
#pragma unroll 1
    for (int tt = 0; tt < T_LEN; tt += 2) {
        load_x(X1, tt + 1);
        step(tt, X0);
        int nx = tt + 2; if (nx > T_LEN - 1) nx = T_LEN - 1;
        load_x(X0, nx);
        step(tt + 1, X1);
    }
}

extern "C" void kernel_launch(void* const* d_in, const int* in_sizes, int n_in,
                              void* d_out, int out_size, void* d_ws, size_t ws_size,
                              hipStream_t stream) {
    const float* OS    = (const float*)d_in[0];
    const float* IS    = (const float*)d_in[1];
    const float* W_ih0 = (const float*)d_in[2];
    const float* W_hh0 = (const float*)d_in[3];
    const float* b_ih0 = (const float*)d_in[4];
    const float* b_hh0 = (const float*)d_in[5];
    const float* W_ih1 = (const float*)d_in[6];
    const float* W_hh1 = (const float*)d_in[7];
    const float* b_ih1 = (const float*)d_in[8];
    const float* b_hh1 = (const float*)d_in[9];
    float* out = (float*)d_out;

    const size_t H1_BYTES = (size_t)T_LEN * BATCH * 64 * sizeof(float);   // 134 MiB
    const size_t ST_BYTES = (size_t)512 * 64 * sizeof(float);             // 128 KiB
    const size_t SLACK    = (size_t)PF * BATCH * 128 * sizeof(float);     // 1 MiB prefetch overrun

    int C = 0;
    if (ws_size > H1_BYTES + ST_BYTES + SLACK) {
        size_t avail = ws_size - H1_BYTES - ST_BYTES - SLACK;
        for (int nc = 1; nc <= 32; nc <<= 1) {
            size_t xg_bytes = (size_t)2 * (T_LEN / nc) * BATCH * 128 * sizeof(float);
            if (xg_bytes <= avail) { C = T_LEN / nc; break; }
        }
    }

    if (C >= 64) {
        float* h1 = (float*)d_ws;
        float* st = (float*)((char*)d_ws + H1_BYTES);
        float* xg = (float*)((char*)d_ws + H1_BYTES + ST_BYTES);
        dim3 gb(256), rb(64), rg(BATCH, 2);
        for (int t_base = 0; t_base < T_LEN; t_base += C) {
            dim3 gg(C / 16, BATCH);
            hipLaunchKernelGGL((xg_gemm_chunk<0>), gg, gb, 0, stream,
                               OS, IS, (const float*)nullptr, W_ih0, b_ih0, b_hh0, xg, t_base, C);
            hipLaunchKernelGGL((lstm_rec_chunk<0>), rg, rb, 0, stream,
                               xg, W_hh0, h1, st, t_base, C);
        }
        for (int t_base = 0; t_base < T_LEN; t_base += C) {
            dim3 gg(C / 16, BATCH);
            hipLaunchKernelGGL((xg_gemm_chunk<1>), gg, gb, 0, stream,
                               (const float*)nullptr, (const float*)nullptr, h1,
                               W_ih1, b_ih1, b_hh1, xg, t_base, C);
            hipLaunchKernelGGL((lstm_rec_chunk<1>), rg, rb, 0, stream,
                               xg, W_hh1, out, st, t_base, C);
        }
    } else {
        float* h1 = (float*)d_ws;
        dim3 grid(BATCH, 2), block(64);
        hipLaunchKernelGGL((lstm_rec<0>), grid, block, 0, stream,
                           OS, IS, W_ih0, W_hh0, b_ih0, b_hh0, (const float*)nullptr, h1);
        hipLaunchKernelGGL((lstm_rec<1>), grid, block, 0, stream,
                           (const float*)nullptr, (const float*)nullptr,
                           W_ih1, W_hh1, b_ih1, b_hh1, (const float*)h1, out);
    }
}